// Round 7
// baseline (179.392 us; speedup 1.0000x reference)
//
#include <hip/hip_runtime.h>
#include <math.h>

#define HOP       128
#define NBINS     257
#define NFRAMES   4000
#define NB        16
#define OUT_LEN   512383          // (4000-1)*128 + 512 - 1
#define CPR       32              // chunks per range (per wave)
#define RPB       126             // ranges per batch = ceil(4003/32)
#define NCHUNK    4003            // output chunks of 128 (last has 127 samples)
#define NQUADS    9               // frame-quads per wave = (CPR+4)/4
#define PBF4      320             // per-wave LDS scratch (float4) per buffer

__device__ __forceinline__ float2 cmul(float2 a, float2 b) {
    return make_float2(a.x*b.x - a.y*b.y, a.x*b.y + a.y*b.x);
}

// Inverse-sign DFT4: y[t] = sum_j x[j] * i^(j*t)
__device__ __forceinline__ void dft4(const float2* x, float2* y) {
    const float s0r=x[0].x+x[2].x, s0i=x[0].y+x[2].y;
    const float d0r=x[0].x-x[2].x, d0i=x[0].y-x[2].y;
    const float s1r=x[1].x+x[3].x, s1i=x[1].y+x[3].y;
    const float d1r=x[1].x-x[3].x, d1i=x[1].y-x[3].y;
    y[0]=make_float2(s0r+s1r, s0i+s1i);
    y[2]=make_float2(s0r-s1r, s0i-s1i);
    y[1]=make_float2(d0r-d1i, d0i+d1r);   // d0 + i*d1
    y[3]=make_float2(d0r+d1i, d0i-d1r);   // d0 - i*d1
}

// Real-packed iSTFT, 4-frame-per-pass (pk8): TWO independent 2-frame-packed
// 256-pt inverse FFTs per pass, each in its own float4 LDS buffer, program-
// order interleaved so buffer-1's DFT math fills buffer-0's lgkmcnt stalls.
// Shuffle-mirror (r6): Y[256-k] = lane-reversed Y[k] via ds_bpermute, halves
// global loads and prefetch registers.  Register OLA; no barriers.
//
// OCCUPANCY MODEL (validated r0-r6): waves/EU = floor(256 / VGPR_Count);
//   launch_bounds(256,N) caps allocator at floor(256/N) VGPRs.
//   Spill ledger: cap32 -> 293us; cap64 -> 160us; cap85 w/ demand 92 -> 81us;
//   demand must fit cap WITH SLACK (r5 lesson).
//   r6: 72 VGPR @ cap85, zero spill, 64.9us, VALUBusy 30.6% -> still
//   latency-bound on 3 dependent LDS round-trips/pass.
//
// THIS ROUND: double ILP per pass (2 independent FFT chains), not occupancy.
//   Demand ~105-120 fits (256,2)=cap128 with slack.  LDS 81920 B/block ->
//   exactly 2 blocks/CU = 8 waves/CU = today's effective occupancy, so the
//   2x ILP is free.  waves x ILP: 8x4 = 32 vs r6's 11x2 = 22.
//
// CPR LEDGER: r3 CPR=8 halo 1.5x; r4 CPR=16 two ragged fills (regression);
//   r6 CPR=22 single fill @12/CU.  r7 CPR=32: 2016 waves <= 2048 slots
//   (8 waves/CU) -> single co-resident fill, halo 36/32 = 1.125x.
__global__ __launch_bounds__(256, 2)
void istft_pk8_kernel(const float* __restrict__ re,
                      const float* __restrict__ im,
                      float* __restrict__ out)
{
    __shared__ float4 buf[4][4][PBF4];   // [wave][buffer][slot] = 81920 B/block
    // 2 blocks/CU * 81920 = 163840 B = exactly the 160 KiB LDS/CU.

    const int tid = threadIdx.x;
    const int wv  = tid >> 6;
    const int l   = tid & 63;
    float4* const W0 = buf[wv][0];
    float4* const W1 = buf[wv][1];
    float4* const W2 = buf[wv][2];
    float4* const W3 = buf[wv][3];

    const int rid = blockIdx.x * 4 + wv;     // 0..2015 exact
    const int b   = rid / RPB;
    const int rr  = rid - b * RPB;
    const int c0  = rr * CPR;
    const int fend = min(c0 + CPR - 1, NCHUNK - 1);

    const float* __restrict__ reb = re + (size_t)b * NFRAMES * NBINS;
    const float* __restrict__ imb = im + (size_t)b * NFRAMES * NBINS;
    float* __restrict__ outb = out + (size_t)b * OUT_LEN;

    // ---- frame-invariant per-lane constants (persistent minimal set;
    //      squares/cubes remat per use) ----
    const float TWO_PI = 6.2831853071795864f;
    const float RQ = 0.70710678118654752f;
    float2 ctw0;
    { float s, c; __sincosf(TWO_PI * (float)l * (1.0f/512.0f), &s, &c);
      ctw0 = make_float2(c, s); }
    float2 w1;
    { float s, c; __sincosf(TWO_PI * (float)l * (1.0f/256.0f), &s, &c);
      w1 = make_float2(c, s); }
    float2 b1;
    { float s, c; __sincosf(TWO_PI * (float)(l & 15) * (1.0f/64.0f), &s, &c);
      b1 = make_float2(c, s); }
    float2 q1;
    { float s, c; __sincosf(TWO_PI * (float)(l & 3) * (1.0f/16.0f), &s, &c);
      q1 = make_float2(c, s); }
    // Window weights; Hann identity keeps only o=0,1 persistent.
    const float S2 = 1.3020833333e-3f;    // 2 * 0.5/768
    float wwx0, wwx1, wwy0, wwy1;
    {
        const float S = 6.5104166667e-4f;   // 0.5/768
        float sx, cx; __sincosf(TWO_PI * (float)(2*l) * (1.0f/512.0f), &sx, &cx);
        wwx0 = S*(1.0f-cx); wwx1 = S*(1.0f+sx);
        float sy, cy; __sincosf(TWO_PI * (float)(2*l+1) * (1.0f/512.0f), &sy, &cy);
        wwy0 = S*(1.0f-cy); wwy1 = S*(1.0f+sy);
    }
    // Transpose layouts (float4 index; conflict profile known-minor).
    const int a1w = l;                                        // + 64*t0
    const int a1r = (l & 15) + 64 * (l >> 4);                 // + 16*q
    const int a2w = (l & 15) + 20 * (l >> 4);                 // + 80*t1
    const int a2r = (l & 3) + 20 * ((l >> 2) & 3) + 80 * (l >> 4);   // + 4*r
    const int a3w = ((l >> 2) & 3) + 4 * (l >> 4) + 20 * (l & 3);    // + 80*t2
    const int a3r = (l & 3) + 4 * ((l >> 2) & 3) + 80 * (l >> 4);    // + 20*k0
    const int revl = (64 - l) & 63;                           // mirror src lane

    float accx[4], accy[4];
    #pragma unroll
    for (int o = 0; o < 4; ++o) { accx[o] = 0.0f; accy[o] = 0.0f; }

    // Raw prefetch registers for the next QUAD of frames (k-side only;
    // mirrors reconstructed by shuffle at consumption).  40 VGPRs.
    float dr[4][4], di[4][4];
    float nyr[4], nyi[4];

    // Load frames fq, fq+1 into prefetch slots s0, s0+1 (s0 constant at
    // every call site -> fully unrolled, all indices compile-time).
    auto load2 = [&](int fq, int s0) {
        #pragma unroll
        for (int h = 0; h < 2; ++h) {
            const int fc = min(max(fq + h, 0), NFRAMES - 1);
            const float* __restrict__ rb = reb + (size_t)fc * NBINS;
            const float* __restrict__ ib = imb + (size_t)fc * NBINS;
            #pragma unroll
            for (int j = 0; j < 4; ++j) {
                const int k = l + 64*j;
                dr[s0+h][j] = rb[k]; di[s0+h][j] = ib[k];
            }
            nyr[s0+h] = rb[256]; nyi[s0+h] = ib[256];
        }
    };

    // Stage-1 math for one frame: shuffle-mirror + pack + dft4 + w-twiddles.
    auto s1frame = [&](const float* dr_, const float* di_, float nr, float ni,
                       float2 w2t, float2 w3t, float2* A) {
        float mr_[4], mi_[4];
        #pragma unroll
        for (int j = 0; j < 4; ++j) {
            float vr = __shfl(dr_[3-j], revl, 64);
            float vi = __shfl(di_[3-j], revl, 64);
            if (j == 0) {
                if (l == 0) { vr = nr; vi = ni; }
            } else {
                if (l == 0) { vr = dr_[4-j]; vi = di_[4-j]; }
            }
            mr_[j] = vr; mi_[j] = vi;
        }
        float2 Cv[4];
        float cc = ctw0.x, ss = ctw0.y;   // walking twiddle, pi/4 per j-step
        #pragma unroll
        for (int j = 0; j < 4; ++j) {
            float ydr = dr_[j], ydi = di_[j], ymr = mr_[j], ymi = mi_[j];
            if (j == 0) {                       // k==0: Im of DC & Nyquist ignored
                const bool z = (l == 0);
                ydi = z ? 0.0f : ydi;
                ymi = z ? 0.0f : ymi;
            }
            const float er  = ydr + ymr, ei  = ydi - ymi;
            const float fr2 = ydr - ymr, fi2 = ydi + ymi;
            const float gr = cc*fr2 - ss*fi2;
            const float gi = cc*fi2 + ss*fr2;
            Cv[j] = make_float2(er - gi, ei + gr);
            const float cn = (cc - ss) * RQ, sn = (ss + cc) * RQ;  // rotate pi/4
            cc = cn; ss = sn;
        }
        dft4(Cv, A);
        A[1] = cmul(A[1], w1); A[2] = cmul(A[2], w2t); A[3] = cmul(A[3], w3t);
    };

    // Stage 1 for the quad: frames 0,1 -> P0; frames 2,3 -> P1.
    auto stage1q = [&](float4* __restrict__ P0, float4* __restrict__ P1) {
        const float2 w2t = cmul(w1, w1);
        const float2 w3t = cmul(w2t, w1);
        float2 Aa[4], Ab[4];
        s1frame(dr[0], di[0], nyr[0], nyi[0], w2t, w3t, Aa);
        s1frame(dr[1], di[1], nyr[1], nyi[1], w2t, w3t, Ab);
        #pragma unroll
        for (int j = 0; j < 4; ++j)
            P0[a1w + 64*j] = make_float4(Aa[j].x, Aa[j].y, Ab[j].x, Ab[j].y);
        s1frame(dr[2], di[2], nyr[2], nyi[2], w2t, w3t, Aa);
        s1frame(dr[3], di[3], nyr[3], nyi[3], w2t, w3t, Ab);
        #pragma unroll
        for (int j = 0; j < 4; ++j)
            P1[a1w + 64*j] = make_float4(Aa[j].x, Aa[j].y, Ab[j].x, Ab[j].y);
    };

    // Stage 2 for one buffer.
    auto st2 = [&](float4* __restrict__ P) {
        float2 Ga[4], Gb[4], Aa[4], Ab[4];
        #pragma unroll
        for (int t = 0; t < 4; ++t) {
            const float4 g = P[a1r + 16*t];
            Ga[t] = make_float2(g.x, g.y); Gb[t] = make_float2(g.z, g.w);
        }
        dft4(Ga, Aa); dft4(Gb, Ab);
        const float2 b2t = cmul(b1, b1);
        const float2 b3t = cmul(b2t, b1);
        Aa[1]=cmul(Aa[1],b1); Aa[2]=cmul(Aa[2],b2t); Aa[3]=cmul(Aa[3],b3t);
        Ab[1]=cmul(Ab[1],b1); Ab[2]=cmul(Ab[2],b2t); Ab[3]=cmul(Ab[3],b3t);
        #pragma unroll
        for (int t = 0; t < 4; ++t)
            P[a2w + 80*t] = make_float4(Aa[t].x, Aa[t].y, Ab[t].x, Ab[t].y);
    };

    // Stage 3 for one buffer.
    auto st3 = [&](float4* __restrict__ P) {
        float2 Ga[4], Gb[4], Aa[4], Ab[4];
        #pragma unroll
        for (int t = 0; t < 4; ++t) {
            const float4 g = P[a2r + 4*t];
            Ga[t] = make_float2(g.x, g.y); Gb[t] = make_float2(g.z, g.w);
        }
        dft4(Ga, Aa); dft4(Gb, Ab);
        const float2 q2t = cmul(q1, q1);
        const float2 q3t = cmul(q2t, q1);
        Aa[1]=cmul(Aa[1],q1); Aa[2]=cmul(Aa[2],q2t); Aa[3]=cmul(Aa[3],q3t);
        Ab[1]=cmul(Ab[1],q1); Ab[2]=cmul(Ab[2],q2t); Ab[3]=cmul(Ab[3],q3t);
        #pragma unroll
        for (int t = 0; t < 4; ++t)
            P[a3w + 80*t] = make_float4(Aa[t].x, Aa[t].y, Ab[t].x, Ab[t].y);
    };

    // OLA accumulate + emit + rotate for one frame.
    auto olaframe = [&](const float2* A, int f) {
        if (f >= 0 && f < NFRAMES) {            // wave-uniform gate
            accx[0] = fmaf(A[0].x, wwx0, accx[0]);
            accx[1] = fmaf(A[1].x, wwx1, accx[1]);
            accx[2] = fmaf(A[2].x, S2, fmaf(-A[2].x, wwx0, accx[2]));
            accx[3] = fmaf(A[3].x, S2, fmaf(-A[3].x, wwx1, accx[3]));
            accy[0] = fmaf(A[0].y, wwy0, accy[0]);
            accy[1] = fmaf(A[1].y, wwy1, accy[1]);
            accy[2] = fmaf(A[2].y, S2, fmaf(-A[2].y, wwy0, accy[2]));
            accy[3] = fmaf(A[3].y, S2, fmaf(-A[3].y, wwy1, accy[3]));
        }
        if (f >= c0 && f <= fend) {             // emit chunk f (complete now)
            const int s0 = f * HOP + 2*l;       // max 512382 < OUT_LEN
            outb[s0] = accx[0];
            const int s1 = s0 + 1;
            if (s1 < OUT_LEN) outb[s1] = accy[0];
        }
        #pragma unroll
        for (int o = 0; o < 3; ++o) { accx[o] = accx[o+1]; accy[o] = accy[o+1]; }
        accx[3] = 0.0f; accy[3] = 0.0f;
    };

    // Stage 4 + OLA for one buffer (frames fa, fa+1 packed in .xy/.zw).
    auto st4ola = [&](float4* __restrict__ P, int fa) {
        float2 Ga[4], Gb[4], Aa[4], Ab[4];
        #pragma unroll
        for (int t = 0; t < 4; ++t) {
            const float4 g = P[a3r + 20*t];
            Ga[t] = make_float2(g.x, g.y); Gb[t] = make_float2(g.z, g.w);
        }
        dft4(Ga, Aa); dft4(Gb, Ab);
        olaframe(Aa, fa);
        olaframe(Ab, fa + 1);
    };

    // ---- software-pipelined quad loop: frames c0-4 .. c0+CPR-1 ----
    // (3-frame warm-up halo + 1 wasted frame, load-clamped + acc/emit-gated.)
    const int base = c0 - 4;
    load2(base, 0); load2(base + 2, 2);
    stage1q(W0, W1);
    float4 *cur0 = W0, *cur1 = W1, *nxt0 = W2, *nxt1 = W3;
    #pragma unroll 1
    for (int q = 0; q < NQUADS; ++q) {
        const int fq = base + 4*q;
        const bool more = (q + 1 < NQUADS);
        if (more) load2(fq + 4, 0);     // next-quad frames 0,1 in flight
        st2(cur0); st2(cur1);           // independent chains interleave
        if (more) load2(fq + 6, 2);     // next-quad frames 2,3 in flight
        st3(cur0); st3(cur1);
        st4ola(cur0, fq); st4ola(cur1, fq + 2);
        if (more) stage1q(nxt0, nxt1);  // consumes next-quad loads
        float4* t;
        t = cur0; cur0 = nxt0; nxt0 = t;
        t = cur1; cur1 = nxt1; nxt1 = t;
    }
}

extern "C" void kernel_launch(void* const* d_in, const int* in_sizes, int n_in,
                              void* d_out, int out_size, void* d_ws, size_t ws_size,
                              hipStream_t stream) {
    (void)in_sizes; (void)n_in; (void)d_ws; (void)ws_size; (void)out_size;
    const float* re = (const float*)d_in[0];
    const float* im = (const float*)d_in[1];
    float* out = (float*)d_out;

    // 16 batches x 126 ranges = 2016 waves; 4 waves per 256-thread block.
    // 504 blocks <= 512 slots (2 blocks/CU, LDS-exact) -> single co-resident
    // fill at 8 waves/CU.
    const int nblocks = (NB * RPB) / 4;   // 504
    istft_pk8_kernel<<<dim3(nblocks), dim3(256), 0, stream>>>(re, im, out);
}

// Round 8
// 162.819 us; speedup vs baseline: 1.1018x; 1.1018x over previous
//
#include <hip/hip_runtime.h>
#include <math.h>

#define HOP       128
#define NBINS     257
#define NFRAMES   4000
#define NB        16
#define OUT_LEN   512383          // (4000-1)*128 + 512 - 1
#define CPR       33              // chunks per range (per wave)
#define RPB       122             // ranges per batch = ceil(4003/33)
#define NCHUNK    4003            // output chunks of 128 (last has 127 samples)
#define NPAIRS    18              // frame-pairs per wave = (CPR+3)/2
#define PBF4      320             // per-wave LDS scratch (float4) per buffer

__device__ __forceinline__ float2 cmul(float2 a, float2 b) {
    return make_float2(a.x*b.x - a.y*b.y, a.x*b.y + a.y*b.x);
}

// Inverse-sign DFT4: y[t] = sum_j x[j] * i^(j*t)
__device__ __forceinline__ void dft4(const float2* x, float2* y) {
    const float s0r=x[0].x+x[2].x, s0i=x[0].y+x[2].y;
    const float d0r=x[0].x-x[2].x, d0i=x[0].y-x[2].y;
    const float s1r=x[1].x+x[3].x, s1i=x[1].y+x[3].y;
    const float d1r=x[1].x-x[3].x, d1i=x[1].y-x[3].y;
    y[0]=make_float2(s0r+s1r, s0i+s1i);
    y[2]=make_float2(s0r-s1r, s0i-s1i);
    y[1]=make_float2(d0r-d1i, d0i+d1r);   // d0 + i*d1
    y[3]=make_float2(d0r+d1i, d0i-d1r);   // d0 - i*d1
}

// Real-packed iSTFT, 2-frame-paired packed 256-pt inverse FFTs (.xy/.zw of
// float4 LDS slots, b128 transposes), shuffle-mirror, register OLA, no barriers.
//
// REGIME MODEL (validated r3/r6/r7): wall per frame-pair per CU is ~CONSTANT
// (1010/1052/1253 cy) across waves 7.9-11.4/CU and ILP 1-2.  Waves self-
// synchronize on the shared per-CU LDS pipe (convoy): VALU ~30% + LDS pipe
// ~36% + conflicts ~10% roughly SUM.  TLP and ILP are exhausted levers;
// the only lever left is TOTAL WORK = pairs x work/pair.  ILP-2 (r7 pk8)
// actively hurt (+200 cy/pair scheduling overhead) -- do not revisit.
//
// OCCUPANCY/SPILL LEDGER: launch_bounds(256,N) caps VGPR at 256/N; demand
// must fit WITH SLACK.  cap32 -> 293us; cap64 -> 160us; cap85 w/ demand 92
// -> 81us; (256,3) w/ demand 72 -> zero spill (r6, 64.9us).  Keep (256,3).
//
// THIS ROUND: pure work reduction, structure untouched.
//   (a) CPR 22 -> 33 (halo amortized over more chunks)
//   (b) halo base c0-4 -> c0-3: the 4th warm-up frame was pair-parity
//       padding only; pairs can start at any parity.  36 frames = 18 pairs
//       cover 33 chunks exactly.
//   pairs: 37856 -> 35136 (-7.2%).  1952 waves = 7.6/CU (r3: 1-chain
//   per-pair wall is fine at ~8 waves/CU).
__global__ __launch_bounds__(256, 3)
void istft_pk4_kernel(const float* __restrict__ re,
                      const float* __restrict__ im,
                      float* __restrict__ out)
{
    __shared__ float4 bufA[4][PBF4];   // 4 waves * 320 * 16 B = 20480 B
    __shared__ float4 bufB[4][PBF4];   // total 40960 B / block

    const int tid = threadIdx.x;
    const int wv  = tid >> 6;
    const int l   = tid & 63;
    float4* PA = bufA[wv];
    float4* PBp = bufB[wv];

    const int rid = blockIdx.x * 4 + wv;     // 0..1951 exact
    const int b   = rid / RPB;
    const int rr  = rid - b * RPB;
    const int c0  = rr * CPR;
    const int fend = min(c0 + CPR - 1, NCHUNK - 1);

    const float* __restrict__ reb = re + (size_t)b * NFRAMES * NBINS;
    const float* __restrict__ imb = im + (size_t)b * NFRAMES * NBINS;
    float* __restrict__ outb = out + (size_t)b * OUT_LEN;

    // ---- frame-invariant per-lane constants (persistent set minimal:
    //      ctw0, w1, b1, q1, ww*4; squares/cubes remat per use) ----
    const float TWO_PI = 6.2831853071795864f;
    const float RQ = 0.70710678118654752f;
    float2 ctw0;
    { float s, c; __sincosf(TWO_PI * (float)l * (1.0f/512.0f), &s, &c);
      ctw0 = make_float2(c, s); }
    float2 w1;
    { float s, c; __sincosf(TWO_PI * (float)l * (1.0f/256.0f), &s, &c);
      w1 = make_float2(c, s); }
    float2 b1;
    { float s, c; __sincosf(TWO_PI * (float)(l & 15) * (1.0f/64.0f), &s, &c);
      b1 = make_float2(c, s); }
    float2 q1;
    { float s, c; __sincosf(TWO_PI * (float)(l & 3) * (1.0f/16.0f), &s, &c);
      q1 = make_float2(c, s); }
    // Window weights for samples 2l+128o (x) / 2l+1+128o (y); Hann identity
    // ww[2]=2S-ww[0], ww[3]=2S-ww[1] keeps only o=0,1 persistent.
    const float S2 = 1.3020833333e-3f;    // 2 * 0.5/768
    float wwx0, wwx1, wwy0, wwy1;
    {
        const float S = 6.5104166667e-4f;   // 0.5/768
        float sx, cx; __sincosf(TWO_PI * (float)(2*l) * (1.0f/512.0f), &sx, &cx);
        wwx0 = S*(1.0f-cx); wwx1 = S*(1.0f+sx);
        float sy, cy; __sincosf(TWO_PI * (float)(2*l+1) * (1.0f/512.0f), &sy, &cy);
        wwy0 = S*(1.0f-cy); wwy1 = S*(1.0f+sy);
    }
    // Transpose layouts (float4 index).  Measured ~3.6-3.9M conflict cycles
    // (~10% of wall): consistent with inherent b128 4-way phase aliasing,
    // layout already <=2-way within 16-lane phases -- not actionable.
    const int a1w = l;                                        // + 64*t0
    const int a1r = (l & 15) + 64 * (l >> 4);                 // + 16*q
    const int a2w = (l & 15) + 20 * (l >> 4);                 // + 80*t1
    const int a2r = (l & 3) + 20 * ((l >> 2) & 3) + 80 * (l >> 4);   // + 4*r
    const int a3w = ((l >> 2) & 3) + 4 * (l >> 4) + 20 * (l & 3);    // + 80*t2
    const int a3r = (l & 3) + 4 * ((l >> 2) & 3) + 80 * (l >> 4);    // + 20*k0
    const int revl = (64 - l) & 63;                           // mirror src lane

    float accx[4], accy[4];
    #pragma unroll
    for (int o = 0; o < 4; ++o) { accx[o] = 0.0f; accy[o] = 0.0f; }

    // Raw prefetch registers for the next PAIR of frames (k-side only;
    // mirrors reconstructed by shuffle at consumption).
    float dra[4], dia[4], drb[4], dib[4];
    float nyra, nyia, nyrb, nyib;

    auto issue_loads = [&](int fq) {           // frames fq (a) and fq+1 (b)
        const int fca = min(max(fq,     0), NFRAMES - 1);
        const int fcb = min(max(fq + 1, 0), NFRAMES - 1);
        const float* __restrict__ rba = reb + (size_t)fca * NBINS;
        const float* __restrict__ iba = imb + (size_t)fca * NBINS;
        const float* __restrict__ rbb = reb + (size_t)fcb * NBINS;
        const float* __restrict__ ibb = imb + (size_t)fcb * NBINS;
        #pragma unroll
        for (int j = 0; j < 4; ++j) {
            const int k = l + 64*j;
            dra[j] = rba[k]; dia[j] = iba[k];
            drb[j] = rbb[k]; dib[j] = ibb[k];
        }
        nyra = rba[256]; nyia = iba[256];      // Nyquist bin (uniform line)
        nyrb = rbb[256]; nyib = ibb[256];
    };

    // Stage-1 math for one frame: shuffle-mirror + pack + dft4 + w-twiddles.
    auto s1frame = [&](const float* dr_, const float* di_, float nyr, float nyi,
                       float2 w2t, float2 w3t, float2* A) {
        // Reconstruct Y[256-k]: lane-reversal shuffle of the k-side loads.
        float mr_[4], mi_[4];
        #pragma unroll
        for (int j = 0; j < 4; ++j) {
            float vr = __shfl(dr_[3-j], revl, 64);
            float vi = __shfl(di_[3-j], revl, 64);
            if (j == 0) {
                if (l == 0) { vr = nyr; vi = nyi; }
            } else {
                if (l == 0) { vr = dr_[4-j]; vi = di_[4-j]; }
            }
            mr_[j] = vr; mi_[j] = vi;
        }
        float2 Cv[4];
        float cc = ctw0.x, ss = ctw0.y;   // walking twiddle, pi/4 per j-step
        #pragma unroll
        for (int j = 0; j < 4; ++j) {
            float ydr = dr_[j], ydi = di_[j], ymr = mr_[j], ymi = mi_[j];
            if (j == 0) {                       // k==0: Im of DC & Nyquist ignored
                const bool z = (l == 0);
                ydi = z ? 0.0f : ydi;
                ymi = z ? 0.0f : ymi;
            }
            const float er  = ydr + ymr, ei  = ydi - ymi;
            const float fr2 = ydr - ymr, fi2 = ydi + ymi;
            const float gr = cc*fr2 - ss*fi2;
            const float gi = cc*fi2 + ss*fr2;
            Cv[j] = make_float2(er - gi, ei + gr);
            const float cn = (cc - ss) * RQ, sn = (ss + cc) * RQ;  // rotate pi/4
            cc = cn; ss = sn;
        }
        dft4(Cv, A);
        A[1] = cmul(A[1], w1); A[2] = cmul(A[2], w2t); A[3] = cmul(A[3], w3t);
    };

    auto stage1 = [&](float4* __restrict__ P) {
        const float2 w2t = cmul(w1, w1);       // transient remat (reg slack)
        const float2 w3t = cmul(w2t, w1);
        float2 Aa[4], Ab[4];
        s1frame(dra, dia, nyra, nyia, w2t, w3t, Aa);
        s1frame(drb, dib, nyrb, nyib, w2t, w3t, Ab);
        #pragma unroll
        for (int j = 0; j < 4; ++j)
            P[a1w + 64*j] = make_float4(Aa[j].x, Aa[j].y, Ab[j].x, Ab[j].y);
    };

    auto stages234 = [&](float4* __restrict__ P, int fa) {
        float2 Ga[4], Gb[4], Aa[4], Ab[4];
        // ---- stage 2 ----
        #pragma unroll
        for (int t = 0; t < 4; ++t) {
            const float4 g = P[a1r + 16*t];
            Ga[t] = make_float2(g.x, g.y); Gb[t] = make_float2(g.z, g.w);
        }
        dft4(Ga, Aa); dft4(Gb, Ab);
        {
            const float2 b2t = cmul(b1, b1);   // transient remat
            const float2 b3t = cmul(b2t, b1);
            Aa[1]=cmul(Aa[1],b1); Aa[2]=cmul(Aa[2],b2t); Aa[3]=cmul(Aa[3],b3t);
            Ab[1]=cmul(Ab[1],b1); Ab[2]=cmul(Ab[2],b2t); Ab[3]=cmul(Ab[3],b3t);
        }
        #pragma unroll
        for (int t = 0; t < 4; ++t)
            P[a2w + 80*t] = make_float4(Aa[t].x, Aa[t].y, Ab[t].x, Ab[t].y);
        // ---- stage 3 ----
        #pragma unroll
        for (int t = 0; t < 4; ++t) {
            const float4 g = P[a2r + 4*t];
            Ga[t] = make_float2(g.x, g.y); Gb[t] = make_float2(g.z, g.w);
        }
        dft4(Ga, Aa); dft4(Gb, Ab);
        {
            const float2 q2t = cmul(q1, q1);   // transient remat
            const float2 q3t = cmul(q2t, q1);
            Aa[1]=cmul(Aa[1],q1); Aa[2]=cmul(Aa[2],q2t); Aa[3]=cmul(Aa[3],q3t);
            Ab[1]=cmul(Ab[1],q1); Ab[2]=cmul(Ab[2],q2t); Ab[3]=cmul(Ab[3],q3t);
        }
        #pragma unroll
        for (int t = 0; t < 4; ++t)
            P[a3w + 80*t] = make_float4(Aa[t].x, Aa[t].y, Ab[t].x, Ab[t].y);
        // ---- stage 4 ----
        #pragma unroll
        for (int t = 0; t < 4; ++t) {
            const float4 g = P[a3r + 20*t];
            Ga[t] = make_float2(g.x, g.y); Gb[t] = make_float2(g.z, g.w);
        }
        dft4(Ga, Aa); dft4(Gb, Ab);
        // ---- OLA: frame fa first (chunk fa must NOT see frame fb), then fb ----
        const int fb = fa + 1;
        if (fa >= 0 && fa < NFRAMES) {          // wave-uniform gate
            accx[0] = fmaf(Aa[0].x, wwx0, accx[0]);
            accx[1] = fmaf(Aa[1].x, wwx1, accx[1]);
            accx[2] = fmaf(Aa[2].x, S2, fmaf(-Aa[2].x, wwx0, accx[2]));
            accx[3] = fmaf(Aa[3].x, S2, fmaf(-Aa[3].x, wwx1, accx[3]));
            accy[0] = fmaf(Aa[0].y, wwy0, accy[0]);
            accy[1] = fmaf(Aa[1].y, wwy1, accy[1]);
            accy[2] = fmaf(Aa[2].y, S2, fmaf(-Aa[2].y, wwy0, accy[2]));
            accy[3] = fmaf(Aa[3].y, S2, fmaf(-Aa[3].y, wwy1, accy[3]));
        }
        if (fa >= c0 && fa <= fend) {           // emit chunk fa (complete now)
            const int s0 = fa * HOP + 2*l;      // max 512382 < OUT_LEN
            outb[s0] = accx[0];
            const int s1 = s0 + 1;
            if (s1 < OUT_LEN) outb[s1] = accy[0];
        }
        #pragma unroll
        for (int o = 0; o < 3; ++o) { accx[o] = accx[o+1]; accy[o] = accy[o+1]; }
        accx[3] = 0.0f; accy[3] = 0.0f;
        if (fb >= 0 && fb < NFRAMES) {
            accx[0] = fmaf(Ab[0].x, wwx0, accx[0]);
            accx[1] = fmaf(Ab[1].x, wwx1, accx[1]);
            accx[2] = fmaf(Ab[2].x, S2, fmaf(-Ab[2].x, wwx0, accx[2]));
            accx[3] = fmaf(Ab[3].x, S2, fmaf(-Ab[3].x, wwx1, accx[3]));
            accy[0] = fmaf(Ab[0].y, wwy0, accy[0]);
            accy[1] = fmaf(Ab[1].y, wwy1, accy[1]);
            accy[2] = fmaf(Ab[2].y, S2, fmaf(-Ab[2].y, wwy0, accy[2]));
            accy[3] = fmaf(Ab[3].y, S2, fmaf(-Ab[3].y, wwy1, accy[3]));
        }
        if (fb >= c0 && fb <= fend) {
            const int s0 = fb * HOP + 2*l;
            outb[s0] = accx[0];
            const int s1 = s0 + 1;
            if (s1 < OUT_LEN) outb[s1] = accy[0];
        }
        #pragma unroll
        for (int o = 0; o < 3; ++o) { accx[o] = accx[o+1]; accy[o] = accy[o+1]; }
        accx[3] = 0.0f; accy[3] = 0.0f;
    };

    // ---- software-pipelined pair loop: frames c0-3 .. c0+CPR-1 ----
    // (3-frame warm-up halo exactly; acc for chunk c0 complete at f=c0.
    //  Out-of-range frames are load-clamped + acc/emit-gated.)
    const int base = c0 - 3;
    issue_loads(base);
    stage1(PA);
    float4* cur = PA;
    float4* nxt = PBp;
    #pragma unroll 1
    for (int p = 0; p < NPAIRS; ++p) {
        if (p + 1 < NPAIRS) issue_loads(base + 2*(p+1)); // fly during stages234
        stages234(cur, base + 2*p);
        if (p + 1 < NPAIRS) stage1(nxt);                 // consumes p+1 loads
        float4* t = cur; cur = nxt; nxt = t;
    }
}

extern "C" void kernel_launch(void* const* d_in, const int* in_sizes, int n_in,
                              void* d_out, int out_size, void* d_ws, size_t ws_size,
                              hipStream_t stream) {
    (void)in_sizes; (void)n_in; (void)d_ws; (void)ws_size; (void)out_size;
    const float* re = (const float*)d_in[0];
    const float* im = (const float*)d_in[1];
    float* out = (float*)d_out;

    // 16 batches x 122 ranges = 1952 waves; 4 waves per 256-thread block.
    // 488 blocks = 7.6 waves/CU, single co-resident fill.
    const int nblocks = (NB * RPB) / 4;   // 488
    istft_pk4_kernel<<<dim3(nblocks), dim3(256), 0, stream>>>(re, im, out);
}